// Round 5
// baseline (652.702 us; speedup 1.0000x reference)
//
#include <hip/hip_runtime.h>

#define Bb 2
#define Cc 1024
#define CIi 512
#define Nn 6272
#define JH 3136  // j-half per attention block (j-split 2)
#define SCALE (1.0f / 32.0f)

typedef __bf16 bf16;
typedef __bf16 bf16x8 __attribute__((ext_vector_type(8)));
typedef float f32x4 __attribute__((ext_vector_type(4)));
typedef unsigned int u32;
typedef unsigned char u8;
typedef unsigned int u32x4 __attribute__((ext_vector_type(4)));

// async global->LDS, 16B per lane: lds dest = wave-uniform base + lane*16
__device__ __forceinline__ void g2l16(const void* g, void* l) {
  __builtin_amdgcn_global_load_lds(
      (const __attribute__((address_space(1))) u32*)g,
      (__attribute__((address_space(3))) u32*)(size_t)l, 16, 0, 0);
}

// float -> OCP e4m3 (HW conversion, saturating)
__device__ __forceinline__ u8 to_fp8(float v) {
  return (u8)(__builtin_amdgcn_cvt_pk_fp8_f32(v, v, 0, 0) & 0xff);
}

// ---------------------------------------------------------------------------
// Kernel 1: x (B,C,N) fp32 -> xT (B,N,C) bf16  (LDS tile transpose)
// ---------------------------------------------------------------------------
__global__ __launch_bounds__(256) void xpose_kernel(const float* __restrict__ x,
                                                    bf16* __restrict__ xT) {
  __shared__ float tile[32][33];
  int b = blockIdx.z;
  int n0 = blockIdx.x * 32, c0 = blockIdx.y * 32;
  int tn = threadIdx.x & 31, tr = threadIdx.x >> 5;
  const float* xp = x + ((size_t)b * Cc + c0) * Nn + n0;
  for (int i = 0; i < 4; i++) {
    int c = tr + i * 8;
    tile[c][tn] = xp[(size_t)c * Nn + tn];
  }
  __syncthreads();
  bf16* op = xT + ((size_t)b * Nn + n0) * Cc + c0;
  for (int i = 0; i < 4; i++) {
    int n = tr + i * 8;
    op[(size_t)n * Cc + tn] = (bf16)tile[tn][n];
  }
}

// ---------------------------------------------------------------------------
// Kernel 2: fused QKV projection.
//   kT: (B,N,CI) fp8 e4m3 natural; qT: (B,N,CI) fp8 with 8B-chunk XOR swizzle
//   baked in (chunk c of row j stored at c^(j&15)) so attn's global_load_lds
//   staging lands bank-conflict-free for ds_read_b64; v: (B,CI,N) bf16.
// ---------------------------------------------------------------------------
__global__ __launch_bounds__(256) void proj_kernel(
    const bf16* __restrict__ xT, const float* __restrict__ Wk,
    const float* __restrict__ Wq, const float* __restrict__ Wv,
    const float* __restrict__ bk, const float* __restrict__ bq,
    const float* __restrict__ bv, u8* __restrict__ kT8, u8* __restrict__ qT8,
    bf16* __restrict__ vv) {
  int z = blockIdx.z;
  int b = z / 3, proj = z % 3;
  const float* W = proj == 0 ? Wk : (proj == 1 ? Wq : Wv);
  const float* bias = proj == 0 ? bk : (proj == 1 ? bq : bv);
  int m0 = blockIdx.x * 128;
  int d0 = blockIdx.y * 128;
  __shared__ __align__(16) bf16 la[128 * 40];
  __shared__ __align__(16) bf16 lb[128 * 40];
  int tid = threadIdx.x;
  int wave = tid >> 6, lane = tid & 63, quad = lane >> 4, l16 = lane & 15;
  int wm = (wave >> 1) * 64, wn = (wave & 1) * 64;
  int row2 = tid >> 1, half = tid & 1;

  f32x4 acc[4][4] = {};
  const bf16* aSrc = xT + ((size_t)b * Nn + m0) * Cc;
  const float* bSrc = W + (size_t)(d0 + row2) * Cc;

  for (int k0 = 0; k0 < Cc; k0 += 32) {
    const u32x4* ga = (const u32x4*)(aSrc + (size_t)row2 * Cc + k0 + half * 16);
    u32x4 a0 = ga[0], a1 = ga[1];
    const f32x4* gb = (const f32x4*)(bSrc + k0 + half * 16);
    f32x4 w0 = gb[0], w1 = gb[1], w2 = gb[2], w3 = gb[3];
    *(u32x4*)&la[row2 * 40 + half * 16] = a0;
    *(u32x4*)&la[row2 * 40 + half * 16 + 8] = a1;
    bf16x8 p0 = {(bf16)w0[0], (bf16)w0[1], (bf16)w0[2], (bf16)w0[3],
                 (bf16)w1[0], (bf16)w1[1], (bf16)w1[2], (bf16)w1[3]};
    bf16x8 p1 = {(bf16)w2[0], (bf16)w2[1], (bf16)w2[2], (bf16)w2[3],
                 (bf16)w3[0], (bf16)w3[1], (bf16)w3[2], (bf16)w3[3]};
    *(bf16x8*)&lb[row2 * 40 + half * 16] = p0;
    *(bf16x8*)&lb[row2 * 40 + half * 16 + 8] = p1;
    __syncthreads();
    bf16x8 af[4], bfr[4];
    for (int t = 0; t < 4; t++)
      af[t] = *(const bf16x8*)&la[(wm + t * 16 + l16) * 40 + quad * 8];
    for (int t = 0; t < 4; t++)
      bfr[t] = *(const bf16x8*)&lb[(wn + t * 16 + l16) * 40 + quad * 8];
    for (int tm = 0; tm < 4; tm++)
      for (int tn = 0; tn < 4; tn++)
        acc[tm][tn] = __builtin_amdgcn_mfma_f32_16x16x32_bf16(
            af[tm], bfr[tn], acc[tm][tn], 0, 0, 0);
    __syncthreads();
  }
  for (int tn = 0; tn < 4; tn++) {
    int dcol = d0 + wn + tn * 16 + l16;
    float bval = bias[dcol];
    for (int tm = 0; tm < 4; tm++) {
      int nbase = m0 + wm + tm * 16 + quad * 4;
      for (int r = 0; r < 4; r++) {
        float val = acc[tm][tn][r] + bval;
        int nrow = nbase + r;
        if (proj == 0) {
          kT8[((size_t)b * Nn + nrow) * CIi + dcol] = to_fp8(val);
        } else if (proj == 1) {
          int ch = (dcol >> 3) ^ (nrow & 15);  // swizzle for attn LDS staging
          qT8[((size_t)b * Nn + nrow) * CIi + ch * 8 + (dcol & 7)] =
              to_fp8(val);
        } else {
          vv[((size_t)b * CIi + dcol) * Nn + nrow] = (bf16)val;
        }
      }
    }
  }
}

// ---------------------------------------------------------------------------
// Kernel 3: flash attention v11 — deep-wave design (4 waves/SIMD).
//   v10 post-mortem: more blocks duplicated per-block overhead (Q-DMA,
//   K loads, barriers) and regressed. The chain-latency stall (v9 iter
//   11.9k cy vs ~1.5k cy issue work) is hidden by wave CONTEXTS per SIMD,
//   which a bigger block provides without duplicating overhead.
//   v11: block = 1024 thr (16 waves = 4/SIMD), i-tile 128, grid 196.
//   S: waves = 8 wi x 2 wj; wave owns 16i x 32j (kf[16] fp8 = 32 VGPRs,
//   s[2] = 8 regs). PV: wave owns d-slice 32 (oacc[8][2] = 64 acc regs).
//   Per-wave regs ~150 -> large scheduling slack (v9's proven lever).
//   Q dbuf 64 KB fp8 (wave stages 4 rows = 2 g2l16); P 18 KB; LDS 83.5 KB.
//   Both V j-chunks preloaded at iter top; b1 = raw s_barrier + lgkmcnt(0)
//   (Q-DMA stays in flight); b2 = __syncthreads full drain.
//   l needs cross-wj reduce (redw[2][128]) since 2 waves share i-rows.
//   No-max softmax: P = exp(S*scale - 2) (clamp 20).
// ---------------------------------------------------------------------------
__global__ __launch_bounds__(1024, 4) void attn_kernel(
    const u8* __restrict__ kT8, const u8* __restrict__ qT8,
    const bf16* __restrict__ vv, bf16* __restrict__ yp,
    float* __restrict__ ml) {
  int l = blockIdx.x;
  int jh = l & 1, b = (l >> 1) & 1;
  int i0 = (l >> 2) * 128;
  int tid = threadIdx.x;
  int wave = tid >> 6, lane = tid & 63, quad = lane >> 4, l16 = lane & 15;
  int wi = wave & 7, wj = wave >> 3;  // S: 8 i-blocks x 2 j-blocks
  int dw = wave * 32;                 // PV d-slice (512/16 waves)

  __shared__ __align__(16) u8 lq[2][64 * 512];  // 64 KB Q dbuf (fp8)
  __shared__ __align__(16) bf16 Psm[128 * 72];  // 18 KB P, 144B row pitch
  __shared__ float redw[2][128];                // per-wj l partials
  __shared__ float redi[128];                   // 1/l broadcast

  const u8* qb = qT8 + ((size_t)b * Nn + (size_t)jh * JH) * CIi;
  const bf16* vb = vv + (size_t)b * CIi * Nn + (size_t)jh * JH;

  // K fragments: wave's 16 i-rows, full d=512, fp8 (A-operand) = 32 VGPRs
  long kf[16];
  {
    const u8* kp = kT8 + ((size_t)b * Nn + i0 + wi * 16 + l16) * CIi +
                   quad * 8;
#pragma unroll
    for (int kk = 0; kk < 16; kk++)
      kf[kk] = *(const long*)(kp + kk * 32);
  }
  f32x4 oacc[8][2] = {};
  f32x4 l_acc = {};

  // prologue: stage tile 0 (64 rows x 512B); wave stages 4 rows = 2 x 1KB
  {
    const u8* qrow = qb + (size_t)(wave * 4) * CIi + lane * 16;
#pragma unroll
    for (int r = 0; r < 2; r++)
      g2l16(qrow + r * 1024, &lq[0][(wave * 4) * 512 + r * 1024]);
  }
  __syncthreads();

  for (int j0 = 0; j0 < JH; j0 += 64) {
    int t = (j0 >> 6) & 1;
    // V for both PV j-chunks: issue BEFORE the DMA so PV waits leave the
    // Q-DMA in flight until the end-of-iter drain.
    u32x4 vf[2][2];
#pragma unroll
    for (int jc = 0; jc < 2; jc++)
#pragma unroll
      for (int ds = 0; ds < 2; ds++)
        vf[jc][ds] = *(const u32x4*)(vb + (size_t)(dw + ds * 16 + l16) * Nn +
                                     j0 + jc * 32 + quad * 8);
    __builtin_amdgcn_sched_barrier(0);  // pin: V loads before DMA
    // issue DMA of next Q tile into the other buffer (drained at b2)
    if (j0 + 64 < JH) {
      const u8* qrow = qb + (size_t)(j0 + 64 + wave * 4) * CIi + lane * 16;
#pragma unroll
      for (int r = 0; r < 2; r++)
        g2l16(qrow + r * 1024, &lq[t ^ 1][(wave * 4) * 512 + r * 1024]);
    }
    // ---- S phase: wave's 16i x 32j over d=512 ----
    f32x4 s[2] = {};
    {
      const u8* q0 = &lq[t][(wj * 32 + l16) * 512];
      const u8* q1 = q0 + 16 * 512;
#pragma unroll
      for (int kk = 0; kk < 16; kk++) {
        int sl = ((kk * 4 + quad) ^ l16) * 8;
        long qf0 = *(const long*)(q0 + sl);
        long qf1 = *(const long*)(q1 + sl);
        s[0] = __builtin_amdgcn_mfma_f32_16x16x32_fp8_fp8(kf[kk], qf0, s[0],
                                                          0, 0, 0);
        s[1] = __builtin_amdgcn_mfma_f32_16x16x32_fp8_fp8(kf[kk], qf1, s[1],
                                                          0, 0, 0);
      }
    }
    // ---- softmax-lite: P = exp(s*SCALE - 2), no max, no corr ----
    {
#pragma unroll
      for (int jb = 0; jb < 2; jb++)
#pragma unroll
        for (int r = 0; r < 4; r++) {
          float p = __expf(fminf(fmaf(s[jb][r], SCALE, -2.0f), 20.0f));
          l_acc[r] += p;
          int gi = wi * 16 + quad * 4 + r;
          int gj = wj * 32 + jb * 16 + l16;
          Psm[gi * 72 + gj] = (bf16)p;
        }
    }
    // b1: P visible. lgkm only — Q DMA stays in flight (no vmcnt drain).
    asm volatile("s_waitcnt lgkmcnt(0)" ::: "memory");
    __builtin_amdgcn_s_barrier();
    asm volatile("" ::: "memory");

    // ---- PV: wave owns d-slice [dw,dw+32) for all 128 i, 2 j-chunks ----
#pragma unroll
    for (int jc = 0; jc < 2; jc++)
#pragma unroll
      for (int is = 0; is < 8; is++) {
        bf16x8 pf = *(const bf16x8*)&Psm[(is * 16 + l16) * 72 + jc * 32 +
                                         quad * 8];
#pragma unroll
        for (int ds = 0; ds < 2; ds++)
          oacc[is][ds] = __builtin_amdgcn_mfma_f32_16x16x32_bf16(
              pf, __builtin_bit_cast(bf16x8, vf[jc][ds]), oacc[is][ds], 0, 0,
              0);
      }
    __syncthreads();  // b2: P reusable; next Q tile resident (full drain)
  }

  // epilogue: reduce l over 16 j-lanes, then across the 2 wj wave groups
#pragma unroll
  for (int o = 1; o < 16; o <<= 1)
#pragma unroll
    for (int r = 0; r < 4; r++) l_acc[r] += __shfl_xor(l_acc[r], o);
  if (l16 == 0) {
#pragma unroll
    for (int r = 0; r < 4; r++)
      redw[wj][wi * 16 + quad * 4 + r] = l_acc[r];
  }
  __syncthreads();
  if (tid < 128) {
    float s = redw[0][tid] + redw[1][tid];
    ml[(size_t)(jh * Bb + b) * Nn + i0 + tid] = s;
    redi[tid] = 1.0f / s;
  }
  __syncthreads();
  bf16* ypb = yp + ((size_t)jh * Bb + b) * Nn * CIi;
#pragma unroll
  for (int is = 0; is < 8; is++) {
    f32x4 inv = *(const f32x4*)&redi[is * 16 + quad * 4];
#pragma unroll
    for (int ds = 0; ds < 2; ds++)
#pragma unroll
      for (int r = 0; r < 4; r++)
        ypb[(size_t)(i0 + is * 16 + quad * 4 + r) * CIi + dw + ds * 16 + l16] =
            (bf16)(oacc[is][ds][r] * inv[r]);
  }
}

// ---------------------------------------------------------------------------
// Kernel 3b: merge the two j-half partials.
//   Same exp offset (-2) in both halves -> weights are just l0, l1:
//   y = (l0*y0 + l1*y1)/(l0+l1).
// ---------------------------------------------------------------------------
__global__ __launch_bounds__(256) void merge_kernel(const bf16* __restrict__ yp,
                                                    const float* __restrict__ ml,
                                                    bf16* __restrict__ y) {
  int idx = blockIdx.x * 256 + threadIdx.x;  // [0, B*N*64)
  int row = idx >> 6, c = idx & 63;
  float l0 = ml[row];
  float l1 = ml[(size_t)Bb * Nn + row];
  float inv = 1.0f / (l0 + l1);
  float w0 = l0 * inv, w1 = l1 * inv;
  bf16x8 v0 = *(const bf16x8*)&yp[(size_t)row * CIi + c * 8];
  bf16x8 v1 =
      *(const bf16x8*)&yp[(size_t)Bb * Nn * CIi + (size_t)row * CIi + c * 8];
  bf16x8 o;
#pragma unroll
  for (int k = 0; k < 8; k++)
    o[k] = (bf16)(w0 * (float)v0[k] + w1 * (float)v1[k]);
  *(bf16x8*)&y[(size_t)row * CIi + c * 8] = o;
}

// ---------------------------------------------------------------------------
// Kernel 4: out = Wo(1024x512) @ y + bo + x.  (unchanged)
// ---------------------------------------------------------------------------
__global__ __launch_bounds__(256) void out_kernel(
    const bf16* __restrict__ y, const float* __restrict__ Wo,
    const float* __restrict__ bo, const float* __restrict__ x,
    float* __restrict__ out) {
  int b = blockIdx.z;
  int d0 = blockIdx.x * 128;
  int m0 = blockIdx.y * 128;
  __shared__ __align__(16) bf16 la[128 * 40];
  __shared__ __align__(16) bf16 lb[128 * 40];
  int tid = threadIdx.x;
  int wave = tid >> 6, lane = tid & 63, quad = lane >> 4, l16 = lane & 15;
  int wm = (wave >> 1) * 64, wn = (wave & 1) * 64;
  int row2 = tid >> 1, half = tid & 1;
  f32x4 acc[4][4] = {};
  const float* aSrc = Wo + (size_t)(d0 + row2) * CIi;
  const bf16* bSrc = y + ((size_t)b * Nn + m0 + row2) * CIi;
  for (int k0 = 0; k0 < CIi; k0 += 32) {
    const f32x4* ga = (const f32x4*)(aSrc + k0 + half * 16);
    f32x4 w0 = ga[0], w1 = ga[1], w2 = ga[2], w3 = ga[3];
    const u32x4* gb = (const u32x4*)(bSrc + k0 + half * 16);
    u32x4 b0 = gb[0], b1 = gb[1];
    bf16x8 p0 = {(bf16)w0[0], (bf16)w0[1], (bf16)w0[2], (bf16)w0[3],
                 (bf16)w1[0], (bf16)w1[1], (bf16)w1[2], (bf16)w1[3]};
    bf16x8 p1 = {(bf16)w2[0], (bf16)w2[1], (bf16)w2[2], (bf16)w2[3],
                 (bf16)w3[0], (bf16)w3[1], (bf16)w3[2], (bf16)w3[3]};
    *(bf16x8*)&la[row2 * 40 + half * 16] = p0;
    *(bf16x8*)&la[row2 * 40 + half * 16 + 8] = p1;
    *(u32x4*)&lb[row2 * 40 + half * 16] = b0;
    *(u32x4*)&lb[row2 * 40 + half * 16 + 8] = b1;
    __syncthreads();
    bf16x8 af[4], bfr[4];
    for (int t = 0; t < 4; t++)
      af[t] = *(const bf16x8*)&la[(wm + t * 16 + l16) * 40 + quad * 8];
    for (int t = 0; t < 4; t++)
      bfr[t] = *(const bf16x8*)&lb[(wn + t * 16 + l16) * 40 + quad * 8];
    for (int tm = 0; tm < 4; tm++)
      for (int tn = 0; tn < 4; tn++)
        acc[tm][tn] = __builtin_amdgcn_mfma_f32_16x16x32_bf16(
            af[tm], bfr[tn], acc[tm][tn], 0, 0, 0);
    __syncthreads();
  }
  for (int tm = 0; tm < 4; tm++) {
    for (int r = 0; r < 4; r++) {
      int drow = d0 + wm + tm * 16 + quad * 4 + r;
      float bval = bo[drow];
      const float* xrow = x + ((size_t)b * Cc + drow) * Nn;
      float* orow = out + ((size_t)b * Cc + drow) * Nn;
      for (int tn = 0; tn < 4; tn++) {
        int ncol = m0 + wn + tn * 16 + l16;
        orow[ncol] = acc[tm][tn][r] + bval + xrow[ncol];
      }
    }
  }
}

// ---------------------------------------------------------------------------
// Launch.  d_ws: [0,25.7MB) xT (dead after proj) -> reused as yp (2 j-half
// partials, bf16); [25.7,38.5MB) y.  d_out: kT8|qT8 (fp8, 6.42MB each) |
// vv bf16 (12.85MB) scratch (25.7MB total) + ml at +40MB (100KB, within
// 51.38MB), all overwritten by out_kernel last.
// ---------------------------------------------------------------------------
extern "C" void kernel_launch(void* const* d_in, const int* in_sizes, int n_in,
                              void* d_out, int out_size, void* d_ws,
                              size_t ws_size, hipStream_t stream) {
  (void)in_sizes;
  (void)n_in;
  (void)out_size;
  (void)ws_size;
  const float* x = (const float*)d_in[0];
  const float* Wk = (const float*)d_in[1];
  const float* bk = (const float*)d_in[2];
  const float* Wq = (const float*)d_in[3];
  const float* bq = (const float*)d_in[4];
  const float* Wv = (const float*)d_in[5];
  const float* bv = (const float*)d_in[6];
  const float* Wo = (const float*)d_in[7];
  const float* bo = (const float*)d_in[8];
  float* out = (float*)d_out;

  bf16* xT = (bf16*)d_ws;                        // B*N*C  (proj input)
  bf16* yp = (bf16*)d_ws;                        // 2 * B*N*CI partials (alias)
  bf16* y = (bf16*)d_ws + (size_t)Bb * Nn * Cc;  // B*N*CI
  u8* kT8 = (u8*)d_out;
  u8* qT8 = kT8 + (size_t)Bb * Nn * CIi;
  bf16* vv = (bf16*)(qT8 + (size_t)Bb * Nn * CIi);
  float* ml = (float*)((char*)d_out + (size_t)40 * 1024 * 1024);

  xpose_kernel<<<dim3(Nn / 32, Cc / 32, Bb), 256, 0, stream>>>(x, xT);
  proj_kernel<<<dim3(Nn / 128, CIi / 128, 3 * Bb), 256, 0, stream>>>(
      xT, Wk, Wq, Wv, bk, bq, bv, kT8, qT8, vv);
  attn_kernel<<<dim3((Nn / 128) * 2 * Bb), 1024, 0, stream>>>(kT8, qT8, vv, yp,
                                                              ml);
  merge_kernel<<<dim3(Bb * Nn * 64 / 256), 256, 0, stream>>>(yp, ml, y);
  out_kernel<<<dim3(Cc / 128, Nn / 128, Bb), 256, 0, stream>>>(y, Wo, bo, x,
                                                               out);
}

// Round 7
// 483.895 us; speedup vs baseline: 1.3489x; 1.3489x over previous
//
#include <hip/hip_runtime.h>

#define Bb 2
#define Cc 1024
#define CIi 512
#define Nn 6272
#define JH 3136  // j-half per attention block (j-split 2)
#define SCALE (1.0f / 32.0f)

typedef __bf16 bf16;
typedef __bf16 bf16x8 __attribute__((ext_vector_type(8)));
typedef float f32x4 __attribute__((ext_vector_type(4)));
typedef unsigned int u32;
typedef unsigned char u8;
typedef unsigned int u32x4 __attribute__((ext_vector_type(4)));

// async global->LDS, 16B per lane: lds dest = wave-uniform base + lane*16
__device__ __forceinline__ void g2l16(const void* g, void* l) {
  __builtin_amdgcn_global_load_lds(
      (const __attribute__((address_space(1))) u32*)g,
      (__attribute__((address_space(3))) u32*)(size_t)l, 16, 0, 0);
}

// float -> OCP e4m3 (HW conversion, saturating)
__device__ __forceinline__ u8 to_fp8(float v) {
  return (u8)(__builtin_amdgcn_cvt_pk_fp8_f32(v, v, 0, 0) & 0xff);
}

// ---------------------------------------------------------------------------
// Kernel 1: x (B,C,N) fp32 -> xT (B,N,C) bf16  (LDS tile transpose)
// ---------------------------------------------------------------------------
__global__ __launch_bounds__(256) void xpose_kernel(const float* __restrict__ x,
                                                    bf16* __restrict__ xT) {
  __shared__ float tile[32][33];
  int b = blockIdx.z;
  int n0 = blockIdx.x * 32, c0 = blockIdx.y * 32;
  int tn = threadIdx.x & 31, tr = threadIdx.x >> 5;
  const float* xp = x + ((size_t)b * Cc + c0) * Nn + n0;
  for (int i = 0; i < 4; i++) {
    int c = tr + i * 8;
    tile[c][tn] = xp[(size_t)c * Nn + tn];
  }
  __syncthreads();
  bf16* op = xT + ((size_t)b * Nn + n0) * Cc + c0;
  for (int i = 0; i < 4; i++) {
    int n = tr + i * 8;
    op[(size_t)n * Cc + tn] = (bf16)tile[tn][n];
  }
}

// ---------------------------------------------------------------------------
// Kernel 2: fused QKV projection — v2: LDS double-buffer + global prefetch.
//   Old: per K-step {load, ds_write, bar, MFMA, bar} fully serial — every
//   step exposes full L2 latency. New: step k issues k+1's global loads
//   into regs, computes k from buf[cur], then converts/writes buf[cur^1];
//   ONE barrier per step; L2 latency hides under ds_read+MFMA.
//   Outputs unchanged: kT fp8 natural; qT fp8 8B-chunk XOR swizzled
//   (chunk c of row j at c^(j&15)); v (B,CI,N) bf16.
// ---------------------------------------------------------------------------
__global__ __launch_bounds__(256) void proj_kernel(
    const bf16* __restrict__ xT, const float* __restrict__ Wk,
    const float* __restrict__ Wq, const float* __restrict__ Wv,
    const float* __restrict__ bk, const float* __restrict__ bq,
    const float* __restrict__ bv, u8* __restrict__ kT8, u8* __restrict__ qT8,
    bf16* __restrict__ vv) {
  int z = blockIdx.z;
  int b = z / 3, proj = z % 3;
  const float* W = proj == 0 ? Wk : (proj == 1 ? Wq : Wv);
  const float* bias = proj == 0 ? bk : (proj == 1 ? bq : bv);
  int m0 = blockIdx.x * 128;
  int d0 = blockIdx.y * 128;
  __shared__ __align__(16) bf16 la[2][128 * 40];
  __shared__ __align__(16) bf16 lb[2][128 * 40];
  int tid = threadIdx.x;
  int wave = tid >> 6, lane = tid & 63, quad = lane >> 4, l16 = lane & 15;
  int wm = (wave >> 1) * 64, wn = (wave & 1) * 64;
  int row2 = tid >> 1, half = tid & 1;

  f32x4 acc[4][4] = {};
  const bf16* aSrc = xT + ((size_t)b * Nn + m0 + row2) * Cc + half * 16;
  const float* bSrc = W + (size_t)(d0 + row2) * Cc + half * 16;

  u32x4 a0, a1;
  f32x4 w0, w1, w2, w3;
  {
    const u32x4* ga = (const u32x4*)aSrc;
    a0 = ga[0];
    a1 = ga[1];
    const f32x4* gb = (const f32x4*)bSrc;
    w0 = gb[0]; w1 = gb[1]; w2 = gb[2]; w3 = gb[3];
  }
  {
    *(u32x4*)&la[0][row2 * 40 + half * 16] = a0;
    *(u32x4*)&la[0][row2 * 40 + half * 16 + 8] = a1;
    bf16x8 p0 = {(bf16)w0[0], (bf16)w0[1], (bf16)w0[2], (bf16)w0[3],
                 (bf16)w1[0], (bf16)w1[1], (bf16)w1[2], (bf16)w1[3]};
    bf16x8 p1 = {(bf16)w2[0], (bf16)w2[1], (bf16)w2[2], (bf16)w2[3],
                 (bf16)w3[0], (bf16)w3[1], (bf16)w3[2], (bf16)w3[3]};
    *(bf16x8*)&lb[0][row2 * 40 + half * 16] = p0;
    *(bf16x8*)&lb[0][row2 * 40 + half * 16 + 8] = p1;
  }
  __syncthreads();

  const int NSTEP = Cc / 32;
  for (int step = 0; step < NSTEP; step++) {
    int cur = step & 1;
    if (step + 1 < NSTEP) {  // prefetch next K-step's globals into regs
      const u32x4* ga = (const u32x4*)(aSrc + (step + 1) * 32);
      a0 = ga[0];
      a1 = ga[1];
      const f32x4* gb = (const f32x4*)(bSrc + (step + 1) * 32);
      w0 = gb[0]; w1 = gb[1]; w2 = gb[2]; w3 = gb[3];
    }
    bf16x8 af[4], bfr[4];
#pragma unroll
    for (int t = 0; t < 4; t++)
      af[t] = *(const bf16x8*)&la[cur][(wm + t * 16 + l16) * 40 + quad * 8];
#pragma unroll
    for (int t = 0; t < 4; t++)
      bfr[t] = *(const bf16x8*)&lb[cur][(wn + t * 16 + l16) * 40 + quad * 8];
#pragma unroll
    for (int tm = 0; tm < 4; tm++)
#pragma unroll
      for (int tn = 0; tn < 4; tn++)
        acc[tm][tn] = __builtin_amdgcn_mfma_f32_16x16x32_bf16(
            af[tm], bfr[tn], acc[tm][tn], 0, 0, 0);
    if (step + 1 < NSTEP) {  // stage prefetched data into the other buffer
      *(u32x4*)&la[cur ^ 1][row2 * 40 + half * 16] = a0;
      *(u32x4*)&la[cur ^ 1][row2 * 40 + half * 16 + 8] = a1;
      bf16x8 p0 = {(bf16)w0[0], (bf16)w0[1], (bf16)w0[2], (bf16)w0[3],
                   (bf16)w1[0], (bf16)w1[1], (bf16)w1[2], (bf16)w1[3]};
      bf16x8 p1 = {(bf16)w2[0], (bf16)w2[1], (bf16)w2[2], (bf16)w2[3],
                   (bf16)w3[0], (bf16)w3[1], (bf16)w3[2], (bf16)w3[3]};
      *(bf16x8*)&lb[cur ^ 1][row2 * 40 + half * 16] = p0;
      *(bf16x8*)&lb[cur ^ 1][row2 * 40 + half * 16 + 8] = p1;
      __syncthreads();
    }
  }
  for (int tn = 0; tn < 4; tn++) {
    int dcol = d0 + wn + tn * 16 + l16;
    float bval = bias[dcol];
    for (int tm = 0; tm < 4; tm++) {
      int nbase = m0 + wm + tm * 16 + quad * 4;
      for (int r = 0; r < 4; r++) {
        float val = acc[tm][tn][r] + bval;
        int nrow = nbase + r;
        if (proj == 0) {
          kT8[((size_t)b * Nn + nrow) * CIi + dcol] = to_fp8(val);
        } else if (proj == 1) {
          int ch = (dcol >> 3) ^ (nrow & 15);  // swizzle for attn LDS staging
          qT8[((size_t)b * Nn + nrow) * CIi + ch * 8 + (dcol & 7)] =
              to_fp8(val);
        } else {
          vv[((size_t)b * CIi + dcol) * Nn + nrow] = (bf16)val;
        }
      }
    }
  }
}

// ---------------------------------------------------------------------------
// Kernel 3: flash attention v9 — register-slack design (chain-break).
//   (verbatim 242 us kernel from r3; v10/v11 occupancy experiments
//   regressed — oacc is irreducible, 2 fat waves/SIMD is the sweet spot.)
// ---------------------------------------------------------------------------
__global__ __launch_bounds__(512, 2) void attn_kernel(
    const u8* __restrict__ kT8, const u8* __restrict__ qT8,
    const bf16* __restrict__ vv, bf16* __restrict__ yp,
    float* __restrict__ ml) {
  int l = blockIdx.x;
  int jh = l & 1, b = (l >> 1) & 1;
  int i0 = (l >> 2) * 128;
  int tid = threadIdx.x;
  int wave = tid >> 6, lane = tid & 63, quad = lane >> 4, l16 = lane & 15;
  int dw = wave * 64;  // PV d-slice

  __shared__ __align__(16) u8 lq[2][64 * 512];  // 64 KB Q dbuf (fp8)
  __shared__ __align__(16) bf16 Psm[128 * 72];  // 18 KB P, 144B row pitch
  __shared__ float redi[128];                   // 1/l broadcast

  const u8* qb = qT8 + ((size_t)b * Nn + (size_t)jh * JH) * CIi;
  const bf16* vb = vv + (size_t)b * CIi * Nn + (size_t)jh * JH;

  // K fragments: wave's 16 i-rows, full d=512, fp8 (A-operand) = 32 VGPRs
  long kf[16];
  {
    const u8* kp = kT8 + ((size_t)b * Nn + i0 + wave * 16 + l16) * CIi +
                   quad * 8;
#pragma unroll
    for (int kk = 0; kk < 16; kk++)
      kf[kk] = *(const long*)(kp + kk * 32);
  }
  f32x4 oacc[8][4] = {};
  f32x4 l_acc = {};

  // prologue: stage tile 0 (64 rows x 512B); wave stages 8 rows = 4 x 1KB
  {
    const u8* qrow = qb + (size_t)(wave * 8) * CIi + lane * 16;
#pragma unroll
    for (int r = 0; r < 4; r++)
      g2l16(qrow + r * 1024, &lq[0][(wave * 8) * 512 + r * 1024]);
  }
  __syncthreads();

  for (int j0 = 0; j0 < JH; j0 += 64) {
    int t = (j0 >> 6) & 1;
    // V for both PV j-chunks: issue BEFORE the DMA so PV waits are vmcnt(4+)
    // and the Q-DMA stays in flight until the end-of-iter drain.
    u32x4 vf[2][4];
#pragma unroll
    for (int jc = 0; jc < 2; jc++)
#pragma unroll
      for (int ds = 0; ds < 4; ds++)
        vf[jc][ds] = *(const u32x4*)(vb + (size_t)(dw + ds * 16 + l16) * Nn +
                                     j0 + jc * 32 + quad * 8);
    __builtin_amdgcn_sched_barrier(0);  // pin: V loads before DMA
    // issue DMA of next Q tile into the other buffer (drained at b2)
    if (j0 + 64 < JH) {
      const u8* qrow = qb + (size_t)(j0 + 64 + wave * 8) * CIi + lane * 16;
#pragma unroll
      for (int r = 0; r < 4; r++)
        g2l16(qrow + r * 1024, &lq[t ^ 1][(wave * 8) * 512 + r * 1024]);
    }
    // ---- S phase: wave's 16i x 64j over d=512 ----
    f32x4 s[4] = {};
    {
      const u8* q0 = &lq[t][l16 * 512];
#pragma unroll
      for (int kk = 0; kk < 16; kk++) {
        int sl = ((kk * 4 + quad) ^ l16) * 8;
        long qf0 = *(const long*)(q0 + sl);
        long qf1 = *(const long*)(q0 + 16 * 512 + sl);
        long qf2 = *(const long*)(q0 + 32 * 512 + sl);
        long qf3 = *(const long*)(q0 + 48 * 512 + sl);
        s[0] = __builtin_amdgcn_mfma_f32_16x16x32_fp8_fp8(kf[kk], qf0, s[0],
                                                          0, 0, 0);
        s[1] = __builtin_amdgcn_mfma_f32_16x16x32_fp8_fp8(kf[kk], qf1, s[1],
                                                          0, 0, 0);
        s[2] = __builtin_amdgcn_mfma_f32_16x16x32_fp8_fp8(kf[kk], qf2, s[2],
                                                          0, 0, 0);
        s[3] = __builtin_amdgcn_mfma_f32_16x16x32_fp8_fp8(kf[kk], qf3, s[3],
                                                          0, 0, 0);
      }
    }
    // ---- softmax-lite: P = exp(s*SCALE - 2), no max, no corr ----
    {
#pragma unroll
      for (int jb = 0; jb < 4; jb++)
#pragma unroll
        for (int r = 0; r < 4; r++) {
          float p = __expf(fminf(fmaf(s[jb][r], SCALE, -2.0f), 20.0f));
          l_acc[r] += p;
          int gi = wave * 16 + quad * 4 + r;
          int gj = jb * 16 + l16;
          Psm[gi * 72 + gj] = (bf16)p;
        }
    }
    // b1: P visible. lgkm only — Q DMA stays in flight (no vmcnt drain).
    asm volatile("s_waitcnt lgkmcnt(0)" ::: "memory");
    __builtin_amdgcn_s_barrier();
    asm volatile("" ::: "memory");

    // ---- PV: wave owns d-slice [dw,dw+64) for all 128 i, 2 j-chunks ----
#pragma unroll
    for (int jc = 0; jc < 2; jc++)
#pragma unroll
      for (int is = 0; is < 8; is++) {
        bf16x8 pf = *(const bf16x8*)&Psm[(is * 16 + l16) * 72 + jc * 32 +
                                         quad * 8];
#pragma unroll
        for (int ds = 0; ds < 4; ds++)
          oacc[is][ds] = __builtin_amdgcn_mfma_f32_16x16x32_bf16(
              pf, __builtin_bit_cast(bf16x8, vf[jc][ds]), oacc[is][ds], 0, 0,
              0);
      }
    __syncthreads();  // b2: P reusable; next Q tile resident (full drain)
  }

  // epilogue: reduce l over the 16 j-lanes (rows are wave-exclusive)
#pragma unroll
  for (int o = 1; o < 16; o <<= 1)
#pragma unroll
    for (int r = 0; r < 4; r++) l_acc[r] += __shfl_xor(l_acc[r], o);
  if (l16 == 0) {
#pragma unroll
    for (int r = 0; r < 4; r++) {
      int gi = wave * 16 + quad * 4 + r;
      ml[(size_t)(jh * Bb + b) * Nn + i0 + gi] = l_acc[r];
      redi[gi] = 1.0f / l_acc[r];
    }
  }
  __syncthreads();
  bf16* ypb = yp + ((size_t)jh * Bb + b) * Nn * CIi;
#pragma unroll
  for (int is = 0; is < 8; is++) {
    f32x4 inv = *(const f32x4*)&redi[is * 16 + quad * 4];
#pragma unroll
    for (int ds = 0; ds < 4; ds++)
#pragma unroll
      for (int r = 0; r < 4; r++)
        ypb[(size_t)(i0 + is * 16 + quad * 4 + r) * CIi + dw + ds * 16 + l16] =
            (bf16)(oacc[is][ds][r] * inv[r]);
  }
}

// ---------------------------------------------------------------------------
// Kernel 3b: merge the two j-half partials.
//   Same exp offset (-2) in both halves -> weights are just l0, l1:
//   y = (l0*y0 + l1*y1)/(l0+l1).
// ---------------------------------------------------------------------------
__global__ __launch_bounds__(256) void merge_kernel(const bf16* __restrict__ yp,
                                                    const float* __restrict__ ml,
                                                    bf16* __restrict__ y) {
  int idx = blockIdx.x * 256 + threadIdx.x;  // [0, B*N*64)
  int row = idx >> 6, c = idx & 63;
  float l0 = ml[row];
  float l1 = ml[(size_t)Bb * Nn + row];
  float inv = 1.0f / (l0 + l1);
  float w0 = l0 * inv, w1 = l1 * inv;
  bf16x8 v0 = *(const bf16x8*)&yp[(size_t)row * CIi + c * 8];
  bf16x8 v1 =
      *(const bf16x8*)&yp[(size_t)Bb * Nn * CIi + (size_t)row * CIi + c * 8];
  bf16x8 o;
#pragma unroll
  for (int k = 0; k < 8; k++)
    o[k] = (bf16)(w0 * (float)v0[k] + w1 * (float)v1[k]);
  *(bf16x8*)&y[(size_t)row * CIi + c * 8] = o;
}

// ---------------------------------------------------------------------------
// Kernel 4: out = Wo(1024x512) @ y + bo + x — v2: dbuf + global prefetch
//   (same pipelining as proj v2; K=512 -> 16 steps, one barrier per step).
// ---------------------------------------------------------------------------
__global__ __launch_bounds__(256) void out_kernel(
    const bf16* __restrict__ y, const float* __restrict__ Wo,
    const float* __restrict__ bo, const float* __restrict__ x,
    float* __restrict__ out) {
  int b = blockIdx.z;
  int d0 = blockIdx.x * 128;
  int m0 = blockIdx.y * 128;
  __shared__ __align__(16) bf16 la[2][128 * 40];
  __shared__ __align__(16) bf16 lb[2][128 * 40];
  int tid = threadIdx.x;
  int wave = tid >> 6, lane = tid & 63, quad = lane >> 4, l16 = lane & 15;
  int wm = (wave >> 1) * 64, wn = (wave & 1) * 64;
  int row2 = tid >> 1, half = tid & 1;
  f32x4 acc[4][4] = {};
  const float* aSrc = Wo + (size_t)(d0 + row2) * CIi + half * 16;
  const bf16* bSrc = y + ((size_t)b * Nn + m0 + row2) * CIi + half * 16;

  f32x4 w0, w1, w2, w3;
  u32x4 b0, b1;
  {
    const f32x4* ga = (const f32x4*)aSrc;
    w0 = ga[0]; w1 = ga[1]; w2 = ga[2]; w3 = ga[3];
    const u32x4* gb = (const u32x4*)bSrc;
    b0 = gb[0];
    b1 = gb[1];
  }
  {
    bf16x8 p0 = {(bf16)w0[0], (bf16)w0[1], (bf16)w0[2], (bf16)w0[3],
                 (bf16)w1[0], (bf16)w1[1], (bf16)w1[2], (bf16)w1[3]};
    bf16x8 p1 = {(bf16)w2[0], (bf16)w2[1], (bf16)w2[2], (bf16)w2[3],
                 (bf16)w3[0], (bf16)w3[1], (bf16)w3[2], (bf16)w3[3]};
    *(bf16x8*)&la[0][row2 * 40 + half * 16] = p0;
    *(bf16x8*)&la[0][row2 * 40 + half * 16 + 8] = p1;
    *(u32x4*)&lb[0][row2 * 40 + half * 16] = b0;
    *(u32x4*)&lb[0][row2 * 40 + half * 16 + 8] = b1;
  }
  __syncthreads();

  const int NSTEP = CIi / 32;
  for (int step = 0; step < NSTEP; step++) {
    int cur = step & 1;
    if (step + 1 < NSTEP) {
      const f32x4* ga = (const f32x4*)(aSrc + (step + 1) * 32);
      w0 = ga[0]; w1 = ga[1]; w2 = ga[2]; w3 = ga[3];
      const u32x4* gb = (const u32x4*)(bSrc + (step + 1) * 32);
      b0 = gb[0];
      b1 = gb[1];
    }
    bf16x8 af[4], bfr[4];
#pragma unroll
    for (int t = 0; t < 4; t++)
      af[t] = *(const bf16x8*)&la[cur][(wm + t * 16 + l16) * 40 + quad * 8];
#pragma unroll
    for (int t = 0; t < 4; t++)
      bfr[t] = *(const bf16x8*)&lb[cur][(wn + t * 16 + l16) * 40 + quad * 8];
#pragma unroll
    for (int tm = 0; tm < 4; tm++)
#pragma unroll
      for (int tn = 0; tn < 4; tn++)
        acc[tm][tn] = __builtin_amdgcn_mfma_f32_16x16x32_bf16(
            af[tm], bfr[tn], acc[tm][tn], 0, 0, 0);
    if (step + 1 < NSTEP) {
      bf16x8 p0 = {(bf16)w0[0], (bf16)w0[1], (bf16)w0[2], (bf16)w0[3],
                   (bf16)w1[0], (bf16)w1[1], (bf16)w1[2], (bf16)w1[3]};
      bf16x8 p1 = {(bf16)w2[0], (bf16)w2[1], (bf16)w2[2], (bf16)w2[3],
                   (bf16)w3[0], (bf16)w3[1], (bf16)w3[2], (bf16)w3[3]};
      *(bf16x8*)&la[cur ^ 1][row2 * 40 + half * 16] = p0;
      *(bf16x8*)&la[cur ^ 1][row2 * 40 + half * 16 + 8] = p1;
      *(u32x4*)&lb[cur ^ 1][row2 * 40 + half * 16] = b0;
      *(u32x4*)&lb[cur ^ 1][row2 * 40 + half * 16 + 8] = b1;
      __syncthreads();
    }
  }
  for (int tm = 0; tm < 4; tm++) {
    for (int r = 0; r < 4; r++) {
      int drow = d0 + wm + tm * 16 + quad * 4 + r;
      float bval = bo[drow];
      const float* xrow = x + ((size_t)b * Cc + drow) * Nn;
      float* orow = out + ((size_t)b * Cc + drow) * Nn;
      for (int tn = 0; tn < 4; tn++) {
        int ncol = m0 + wn + tn * 16 + l16;
        orow[ncol] = acc[tm][tn][r] + bval + xrow[ncol];
      }
    }
  }
}

// ---------------------------------------------------------------------------
// Launch.  d_ws: [0,25.7MB) xT (dead after proj) -> reused as yp (2 j-half
// partials, bf16); [25.7,38.5MB) y.  d_out: kT8|qT8 (fp8, 6.42MB each) |
// vv bf16 (12.85MB) scratch (25.7MB total) + ml at +40MB (100KB, within
// 51.38MB), all overwritten by out_kernel last.
// ---------------------------------------------------------------------------
extern "C" void kernel_launch(void* const* d_in, const int* in_sizes, int n_in,
                              void* d_out, int out_size, void* d_ws,
                              size_t ws_size, hipStream_t stream) {
  (void)in_sizes;
  (void)n_in;
  (void)out_size;
  (void)ws_size;
  const float* x = (const float*)d_in[0];
  const float* Wk = (const float*)d_in[1];
  const float* bk = (const float*)d_in[2];
  const float* Wq = (const float*)d_in[3];
  const float* bq = (const float*)d_in[4];
  const float* Wv = (const float*)d_in[5];
  const float* bv = (const float*)d_in[6];
  const float* Wo = (const float*)d_in[7];
  const float* bo = (const float*)d_in[8];
  float* out = (float*)d_out;

  bf16* xT = (bf16*)d_ws;                        // B*N*C  (proj input)
  bf16* yp = (bf16*)d_ws;                        // 2 * B*N*CI partials (alias)
  bf16* y = (bf16*)d_ws + (size_t)Bb * Nn * Cc;  // B*N*CI
  u8* kT8 = (u8*)d_out;
  u8* qT8 = kT8 + (size_t)Bb * Nn * CIi;
  bf16* vv = (bf16*)(qT8 + (size_t)Bb * Nn * CIi);
  float* ml = (float*)((char*)d_out + (size_t)40 * 1024 * 1024);

  xpose_kernel<<<dim3(Nn / 32, Cc / 32, Bb), 256, 0, stream>>>(x, xT);
  proj_kernel<<<dim3(Nn / 128, CIi / 128, 3 * Bb), 256, 0, stream>>>(
      xT, Wk, Wq, Wv, bk, bq, bv, kT8, qT8, vv);
  attn_kernel<<<dim3((Nn / 128) * 2 * Bb), 512, 0, stream>>>(kT8, qT8, vv, yp,
                                                             ml);
  merge_kernel<<<dim3(Bb * Nn * 64 / 256), 256, 0, stream>>>(yp, ml, y);
  out_kernel<<<dim3(Cc / 128, Nn / 128, Bb), 256, 0, stream>>>(y, Wo, bo, x,
                                                               out);
}